// Round 9
// baseline (292.759 us; speedup 1.0000x reference)
//
#include <hip/hip_runtime.h>
#include <stdint.h>

// Problem constants (fixed by the reference)
#define BB   2
#define SS   2048
#define DD   768
#define HH   12
#define MM   (BB*SS)          // 4096 rows in all GEMMs

typedef __bf16 v8bf __attribute__((ext_vector_type(8)));   // 8 bf16 = 4 VGPRs (MFMA A/B frag)
typedef float  v4f  __attribute__((ext_vector_type(4)));   // MFMA C/D frag (16x16)

__device__ inline v4f mfma16(v8bf a, v8bf b, v4f c) {
    return __builtin_amdgcn_mfma_f32_16x16x32_bf16(a, b, c, 0, 0, 0);
}

// float -> bf16 bits, round-to-nearest-even
__device__ inline unsigned short f2bf(float f) {
    union { float f; uint32_t u; } v; v.f = f;
    return (unsigned short)((v.u + 0x7FFFu + ((v.u >> 16) & 1u)) >> 16);
}

// 8 contiguous fp32 -> 8 bf16 packed into 16 bytes
__device__ inline uint4 cvt8(const float* __restrict__ p) {
    uint4 out;
    unsigned short* s = (unsigned short*)&out;
#pragma unroll
    for (int j = 0; j < 8; ++j) s[j] = f2bf(p[j]);
    return out;
}

// ---------------------------------------------------------------------------
// NT GEMM: C[m,n] = sum_k A[m,k] * W[n,k]   (A: 4096x768, W: 768x768 fp32 row-major)
// A_BF16: A operand is bf16 (attention output) vs fp32 (X input).
// C_F32:  epilogue writes fp32 (final output) vs bf16 (intermediates).
// Tile 128x128, BK=32, 256 threads = 4 waves 2x2, each wave 64x64 (4x4 MFMA tiles).
// blockIdx.z selects (W,C) so QKV runs as one dispatch.
// Fragment layouts verified on this toolchain by R2(MFMA) == R4(scalar VALU)
// bit-identity: A/B row|col=lane&15, k=(lane>>4)*8+j; C/D col=lane&15, row=(lane>>4)*4+reg.
// ---------------------------------------------------------------------------
template<int A_BF16, int C_F32>
__global__ __launch_bounds__(256) void gemm_nt(
    const void* __restrict__ Ain,
    const float* __restrict__ W0, const float* __restrict__ W1,
    const float* __restrict__ W2,
    void* __restrict__ C0, void* __restrict__ C1, void* __restrict__ C2)
{
    const int K = DD, N = DD;
    const float* W = W0;
    void* C = C0;
    if (blockIdx.z == 1) { W = W1; C = C1; }
    else if (blockIdx.z == 2) { W = W2; C = C2; }

    __shared__ __align__(16) unsigned short As[128 * 32];
    __shared__ __align__(16) unsigned short Bs[128 * 32];

    const int tid  = threadIdx.x;
    const int wave = tid >> 6, lane = tid & 63;
    const int quad = lane >> 4, l16 = lane & 15;
    const int waveM = (wave >> 1) * 64, waveN = (wave & 1) * 64;
    const int m0 = blockIdx.y * 128, n0 = blockIdx.x * 128;

    v4f acc[4][4] = {};

    for (int kt = 0; kt < K; kt += 32) {
        __syncthreads();   // protect previous iteration's LDS reads
#pragma unroll
        for (int p = 0; p < 2; ++p) {
            int e = p * 2048 + tid * 8;     // element index in 128x32 tile
            int r = e >> 5, c = e & 31;
            if (A_BF16) {
                *(uint4*)(&As[e]) =
                    *(const uint4*)((const unsigned short*)Ain + (size_t)(m0 + r) * K + kt + c);
            } else {
                *(uint4*)(&As[e]) = cvt8((const float*)Ain + (size_t)(m0 + r) * K + kt + c);
            }
            *(uint4*)(&Bs[e]) = cvt8(W + (size_t)(n0 + r) * K + kt + c);
        }
        __syncthreads();

        v8bf af[4], bfv[4];
#pragma unroll
        for (int i = 0; i < 4; ++i) {
            af[i]  = *(const v8bf*)(&As[(waveM + i * 16 + l16) * 32 + quad * 8]);
            bfv[i] = *(const v8bf*)(&Bs[(waveN + i * 16 + l16) * 32 + quad * 8]);
        }
#pragma unroll
        for (int mi = 0; mi < 4; ++mi)
#pragma unroll
            for (int ni = 0; ni < 4; ++ni)
                acc[mi][ni] = mfma16(af[mi], bfv[ni], acc[mi][ni]);
    }

    // Epilogue: C/D layout col=l16, row=quad*4+r
#pragma unroll
    for (int mi = 0; mi < 4; ++mi)
#pragma unroll
        for (int ni = 0; ni < 4; ++ni)
#pragma unroll
            for (int r = 0; r < 4; ++r) {
                int row = m0 + waveM + mi * 16 + quad * 4 + r;
                int col = n0 + waveN + ni * 16 + l16;
                if (C_F32)
                    ((float*)C)[(size_t)row * N + col] = acc[mi][ni][r];
                else
                    ((unsigned short*)C)[(size_t)row * N + col] = f2bf(acc[mi][ni][r]);
            }
}

// ---------------------------------------------------------------------------
// Flash-style causal attention over bf16 Q/K/V. Safe in-place (O may alias Q):
// block (q-tile,h,b) reads its own Q rows/head-slice before the K-loop and
// writes exactly those elements in the epilogue; no other block touches them.
// Grid: (S/64 q-tiles, H, B). Block: 256 = 4 waves; wave w owns q-rows [q0+16w,+16).
// ---------------------------------------------------------------------------
__global__ __launch_bounds__(256) void attn_fwd(
    const unsigned short* __restrict__ Q,   // (B,S,D) bf16
    const unsigned short* __restrict__ Kt,  // (B,S,D) bf16
    const unsigned short* __restrict__ V,   // (B,S,D) bf16
    unsigned short* __restrict__ O)         // (B,S,D) bf16
{
    const int b = blockIdx.z, h = blockIdx.y, q0 = blockIdx.x * 64;
    const int tid  = threadIdx.x;
    const int wave = tid >> 6, lane = tid & 63;
    const int quad = lane >> 4, l16 = lane & 15;
    const float scale = 0.125f;   // 1/sqrt(64)

    __shared__ __align__(16) unsigned short Ks[64 * 64];
    __shared__ __align__(16) unsigned short Vt[64 * 64];     // [dk][key]
    __shared__ __align__(16) unsigned short Ps[4][16 * 64];  // per-wave P buffer

    // Preload this wave's Q fragments (16 rows x 64 dk = 2 k-chunks)
    v8bf qf[2];
    {
        int qrow = q0 + wave * 16 + l16;
        const unsigned short* qp = &Q[((size_t)(b * SS + qrow)) * DD + h * 64];
        qf[0] = *(const v8bf*)(qp + quad * 8);
        qf[1] = *(const v8bf*)(qp + 32 + quad * 8);
    }

    v4f oacc[4] = {};
    float m_run[4], l_run[4];
    for (int r = 0; r < 4; ++r) { m_run[r] = -1e30f; l_run[r] = 0.0f; }

    const int ktiles = blockIdx.x + 1;   // causal: keys 0 .. q0+63
    for (int kt = 0; kt < ktiles; ++kt) {
        const int kb = kt * 64;
        __syncthreads();   // protect previous iteration's LDS reads (Ks/Vt/Ps)
#pragma unroll
        for (int p = 0; p < 2; ++p) {
            int e   = p * 2048 + tid * 8;
            int key = e >> 6, dk = e & 63;
            const size_t gbase = ((size_t)(b * SS + kb + key)) * DD + h * 64 + dk;
            *(uint4*)(&Ks[e]) = *(const uint4*)(&Kt[gbase]);
            uint4 vv = *(const uint4*)(&V[gbase]);
            const unsigned short* vs = (const unsigned short*)&vv;
#pragma unroll
            for (int j = 0; j < 8; ++j) Vt[(dk + j) * 64 + key] = vs[j];
        }
        __syncthreads();

        // S = Q K^T (16 q-rows x 64 keys per wave), f32 accumulate
        v4f sacc[4] = {};
#pragma unroll
        for (int nk = 0; nk < 4; ++nk) {
            v8bf k0 = *(const v8bf*)(&Ks[(nk * 16 + l16) * 64 + quad * 8]);
            v8bf k1 = *(const v8bf*)(&Ks[(nk * 16 + l16) * 64 + 32 + quad * 8]);
            sacc[nk] = mfma16(qf[0], k0, sacc[nk]);
            sacc[nk] = mfma16(qf[1], k1, sacc[nk]);
        }

        // scale + causal mask + online softmax (row = quad*4+r; reduce across l16)
        float pv[4][4], tmax[4], tsum[4];
#pragma unroll
        for (int r = 0; r < 4; ++r) {
            int qrow = q0 + wave * 16 + quad * 4 + r;
            float mx = -1e30f;
#pragma unroll
            for (int nk = 0; nk < 4; ++nk) {
                float s = sacc[nk][r] * scale;
                int key = kb + nk * 16 + l16;
                if (key > qrow) s = -1e30f;
                pv[nk][r] = s;
                mx = fmaxf(mx, s);
            }
            tmax[r] = mx;
        }
        for (int off = 1; off < 16; off <<= 1)
#pragma unroll
            for (int r = 0; r < 4; ++r)
                tmax[r] = fmaxf(tmax[r], __shfl_xor(tmax[r], off, 64));
#pragma unroll
        for (int r = 0; r < 4; ++r) {
            float mnew  = fmaxf(m_run[r], tmax[r]);
            float alpha = __expf(m_run[r] - mnew);
            m_run[r] = mnew;
            float s = 0.0f;
#pragma unroll
            for (int nk = 0; nk < 4; ++nk) {
                float p = __expf(pv[nk][r] - mnew);
                pv[nk][r] = p;
                s += p;
            }
            tsum[r] = s;
#pragma unroll
            for (int dt = 0; dt < 4; ++dt) oacc[dt][r] *= alpha;
            l_run[r] *= alpha;
        }
        for (int off = 1; off < 16; off <<= 1)
#pragma unroll
            for (int r = 0; r < 4; ++r)
                tsum[r] += __shfl_xor(tsum[r], off, 64);
#pragma unroll
        for (int r = 0; r < 4; ++r) l_run[r] += tsum[r];

        // P: C-layout regs -> LDS -> A-layout frags (barrier for cross-lane visibility)
        unsigned short* pw = &Ps[wave][0];
#pragma unroll
        for (int nk = 0; nk < 4; ++nk)
#pragma unroll
            for (int r = 0; r < 4; ++r)
                pw[(quad * 4 + r) * 64 + nk * 16 + l16] = f2bf(pv[nk][r]);

        __syncthreads();

#pragma unroll
        for (int kc = 0; kc < 2; ++kc) {
            v8bf pa = *(const v8bf*)(&pw[l16 * 64 + kc * 32 + quad * 8]);
#pragma unroll
            for (int dt = 0; dt < 4; ++dt) {
                v8bf vb = *(const v8bf*)(&Vt[(dt * 16 + l16) * 64 + kc * 32 + quad * 8]);
                oacc[dt] = mfma16(pa, vb, oacc[dt]);
            }
        }
    }

    // Epilogue: O[q][dk] / l_run, write (B,S,D)
#pragma unroll
    for (int dt = 0; dt < 4; ++dt)
#pragma unroll
        for (int r = 0; r < 4; ++r) {
            int qrow = q0 + wave * 16 + quad * 4 + r;
            float o = oacc[dt][r] / l_run[r];
            O[((size_t)(b * SS + qrow)) * DD + h * 64 + dt * 16 + l16] = f2bf(o);
        }
}

// ---------------------------------------------------------------------------
extern "C" void kernel_launch(void* const* d_in, const int* in_sizes, int n_in,
                              void* d_out, int out_size, void* d_ws, size_t ws_size,
                              hipStream_t stream)
{
    // Interface (verified R5 sentinels + R8 probe): inputs fp32 in dict order
    // (X, Wq, Wk, Wv, Wo); output fp32 (B,S,D); ws >= 12.6 MB.
    const float* X  = (const float*)d_in[0];
    const float* Wq = (const float*)d_in[1];
    const float* Wk = (const float*)d_in[2];
    const float* Wv = (const float*)d_in[3];
    const float* Wo = (const float*)d_in[4];
    float* Out = (float*)d_out;

    const size_t msd = (size_t)MM * DD;             // 3,145,728 elements
    // bf16 intermediates: Qb, Kb in d_ws (12.6 MB, verified); V-bf16 in the
    // first half of d_out's 12.58 MB (dead before out-proj overwrites it);
    // attention output in-place into Qb (per-block disjointness, see kernel).
    unsigned short* Qb = (unsigned short*)d_ws;
    unsigned short* Kb = Qb + msd;
    unsigned short* Vb = (unsigned short*)d_out;

    dim3 blk(256);
    dim3 g1(DD / 128, MM / 128, 3);                 // fused QKV projection
    gemm_nt<0, 0><<<g1, blk, 0, stream>>>(X, Wq, Wk, Wv, Qb, Kb, Vb);

    dim3 g2(SS / 64, HH, BB);                       // flash attention, O in-place
    attn_fwd<<<g2, blk, 0, stream>>>(Qb, Kb, Vb, Qb);

    dim3 g3(DD / 128, MM / 128, 1);                 // output projection -> fp32
    gemm_nt<1, 1><<<g3, blk, 0, stream>>>(Qb, Wo, Wo, Wo, Out, Out, Out);
}

// Round 10
// 254.526 us; speedup vs baseline: 1.1502x; 1.1502x over previous
//
#include <hip/hip_runtime.h>
#include <stdint.h>

// Problem constants (fixed by the reference)
#define BB   2
#define SS   2048
#define DD   768
#define HH   12
#define MM   (BB*SS)          // 4096 rows in all GEMMs
#define XSZ  (MM*DD)          // 3,145,728
#define WSZ  (DD*DD)          //   589,824

typedef __bf16 v8bf __attribute__((ext_vector_type(8)));   // 8 bf16 = 4 VGPRs (MFMA A/B frag)
typedef float  v4f  __attribute__((ext_vector_type(4)));   // MFMA C/D frag (16x16)

__device__ inline v4f mfma16(v8bf a, v8bf b, v4f c) {
    return __builtin_amdgcn_mfma_f32_16x16x32_bf16(a, b, c, 0, 0, 0);
}

// float -> bf16 bits, round-to-nearest-even
__device__ inline unsigned short f2bf(float f) {
    union { float f; uint32_t u; } v; v.f = f;
    return (unsigned short)((v.u + 0x7FFFu + ((v.u >> 16) & 1u)) >> 16);
}

// 8 contiguous fp32 -> 8 bf16 packed into 16 bytes (fallback staging path)
__device__ inline uint4 cvt8(const float* __restrict__ p) {
    uint4 out;
    unsigned short* s = (unsigned short*)&out;
#pragma unroll
    for (int j = 0; j < 8; ++j) s[j] = f2bf(p[j]);
    return out;
}

// ---------------------------------------------------------------------------
// Bulk fp32 -> bf16 conversion of X and the four weights (one dispatch).
// Flat index space: [0,XSZ) = X, then 4 x WSZ = Wq,Wk,Wv,Wo. 4 elems/thread.
// Total = 5,505,024 elems = 5376 blocks x 1024 exactly (no guard needed).
// ---------------------------------------------------------------------------
__global__ __launch_bounds__(256) void cvt_all(
    const float* __restrict__ X,  const float* __restrict__ Wq,
    const float* __restrict__ Wk, const float* __restrict__ Wv,
    const float* __restrict__ Wo,
    unsigned short* __restrict__ Xb,  unsigned short* __restrict__ Wqb,
    unsigned short* __restrict__ Wkb, unsigned short* __restrict__ Wvb,
    unsigned short* __restrict__ Wob)
{
    long i4 = ((long)blockIdx.x * 256 + threadIdx.x) * 4;
    const float* s; unsigned short* d; long off;
    if (i4 < XSZ) { s = X; d = Xb; off = i4; }
    else {
        long j = i4 - XSZ;
        int t = (int)(j / WSZ);
        off = j - (long)t * WSZ;
        s = (t == 0) ? Wq : (t == 1) ? Wk : (t == 2) ? Wv : Wo;
        d = (t == 0) ? Wqb : (t == 1) ? Wkb : (t == 2) ? Wvb : Wob;
    }
    float4 v = *(const float4*)(s + off);
    ushort4 o;
    o.x = f2bf(v.x); o.y = f2bf(v.y); o.z = f2bf(v.z); o.w = f2bf(v.w);
    *(ushort4*)(d + off) = o;
}

// ---------------------------------------------------------------------------
// NT GEMM: C[m,n] = sum_k A[m,k] * W[n,k]. 128x128 tile, BK=32, 4 waves 2x2.
// A_BF16 / W_BF16 select bf16 (pre-converted) vs fp32+cvt8 staging.
// C_F32: write fp32 (final output) vs bf16. VT2: blockIdx.z==2 writes V
// TRANSPOSED as (B,H,64,S) for direct global V^T fragment loads in attention.
// Core verified (R9 pass; R2==R4 bit-identity for the fragment layouts).
// ---------------------------------------------------------------------------
template<int A_BF16, int W_BF16, int C_F32, int VT2>
__global__ __launch_bounds__(256) void gemm_u(
    const void* __restrict__ Ain,
    const void* __restrict__ W0, const void* __restrict__ W1,
    const void* __restrict__ W2,
    void* __restrict__ C0, void* __restrict__ C1, void* __restrict__ C2)
{
    const int K = DD, N = DD;
    const void* W = W0;
    void* C = C0;
    if (blockIdx.z == 1) { W = W1; C = C1; }
    else if (blockIdx.z == 2) { W = W2; C = C2; }

    __shared__ __align__(16) unsigned short As[128 * 32];
    __shared__ __align__(16) unsigned short Bs[128 * 32];

    const int tid  = threadIdx.x;
    const int wave = tid >> 6, lane = tid & 63;
    const int quad = lane >> 4, l16 = lane & 15;
    const int waveM = (wave >> 1) * 64, waveN = (wave & 1) * 64;
    const int m0 = blockIdx.y * 128, n0 = blockIdx.x * 128;

    v4f acc[4][4] = {};

    for (int kt = 0; kt < K; kt += 32) {
        __syncthreads();
#pragma unroll
        for (int p = 0; p < 2; ++p) {
            int e = p * 2048 + tid * 8;
            int r = e >> 5, c = e & 31;
            if (A_BF16)
                *(uint4*)(&As[e]) = *(const uint4*)((const unsigned short*)Ain + (size_t)(m0 + r) * K + kt + c);
            else
                *(uint4*)(&As[e]) = cvt8((const float*)Ain + (size_t)(m0 + r) * K + kt + c);
            if (W_BF16)
                *(uint4*)(&Bs[e]) = *(const uint4*)((const unsigned short*)W + (size_t)(n0 + r) * K + kt + c);
            else
                *(uint4*)(&Bs[e]) = cvt8((const float*)W + (size_t)(n0 + r) * K + kt + c);
        }
        __syncthreads();

        v8bf af[4], bfv[4];
#pragma unroll
        for (int i = 0; i < 4; ++i) {
            af[i]  = *(const v8bf*)(&As[(waveM + i * 16 + l16) * 32 + quad * 8]);
            bfv[i] = *(const v8bf*)(&Bs[(waveN + i * 16 + l16) * 32 + quad * 8]);
        }
#pragma unroll
        for (int mi = 0; mi < 4; ++mi)
#pragma unroll
            for (int ni = 0; ni < 4; ++ni)
                acc[mi][ni] = mfma16(af[mi], bfv[ni], acc[mi][ni]);
    }

    // Epilogue: C/D layout col=l16, row=quad*4+r
#pragma unroll
    for (int mi = 0; mi < 4; ++mi)
#pragma unroll
        for (int ni = 0; ni < 4; ++ni)
#pragma unroll
            for (int r = 0; r < 4; ++r) {
                int row = m0 + waveM + mi * 16 + quad * 4 + r;
                int col = n0 + waveN + ni * 16 + l16;
                if (VT2 && blockIdx.z == 2) {
                    // V^T store: (B,H,64,S)[b][h][dk][s] = V[b][s][h*64+dk]
                    int b = row >> 11, s = row & 2047;
                    int h = col >> 6,  dk = col & 63;
                    ((unsigned short*)C)[(((size_t)(b * HH + h)) * 64 + dk) * SS + s] =
                        f2bf(acc[mi][ni][r]);
                } else if (C_F32) {
                    ((float*)C)[(size_t)row * N + col] = acc[mi][ni][r];
                } else {
                    ((unsigned short*)C)[(size_t)row * N + col] = f2bf(acc[mi][ni][r]);
                }
            }
}

// ---------------------------------------------------------------------------
// Wave-flash causal attention. Grid (S/16, H, B) = 3072 blocks, 256 threads.
// Block owns q-rows [qs, qs+16); wave w independently processes k-tiles
// w, w+4, w+8, ... with NO barriers in the loop (per-wave online softmax),
// then the 4 partial (m,l,O) merge once through LDS + one __syncthreads.
// K frags read direct from global (dk-contiguous). V frags read direct from
// the pre-transposed V^T (key-contiguous). P transform via per-wave LDS
// (R2==R4 verified barrier-free; compiler fence prevents reordering).
// Safe in-place O==Q: block reads only its own 16 Q rows first, writes them last.
// ---------------------------------------------------------------------------
__global__ __launch_bounds__(256) void attn_wf(
    const unsigned short* __restrict__ Q,    // (B,S,D) bf16
    const unsigned short* __restrict__ Kg,   // (B,S,D) bf16
    const unsigned short* __restrict__ Vt,   // (B,H,64,S) bf16 transposed
    unsigned short* __restrict__ O)          // (B,S,D) bf16 (may alias Q)
{
    const int b = blockIdx.z, h = blockIdx.y, qs = blockIdx.x * 16;
    const int tid  = threadIdx.x;
    const int wave = tid >> 6, lane = tid & 63;
    const int quad = lane >> 4, l16 = lane & 15;
    const float scale = 0.125f;   // 1/sqrt(64)

    __shared__ __align__(16) unsigned short Ps[4][16 * 72]; // per-wave P buffer
    __shared__ __align__(16) float Ow[4][16 * 65];          // per-wave O partial
    __shared__ float Mw[4][16], Lw[4][16];

    // Q fragments for this block's 16 rows (same for all waves)
    v8bf qf0, qf1;
    {
        const unsigned short* qp = &Q[((size_t)(b * SS + qs + l16)) * DD + h * 64];
        qf0 = *(const v8bf*)(qp + quad * 8);
        qf1 = *(const v8bf*)(qp + 32 + quad * 8);
    }

    v4f oacc[4] = {};
    float m_run[4], l_run[4];
#pragma unroll
    for (int r = 0; r < 4; ++r) { m_run[r] = -1e30f; l_run[r] = 0.0f; }

    const int NT = (qs + 15) / 64 + 1;   // causal: k-tiles covering keys 0..qs+15
    const unsigned short* vrow = &Vt[((size_t)(b * HH + h) * 64) * SS];
    unsigned short* pw = &Ps[wave][0];

    for (int kt = wave; kt < NT; kt += 4) {
        const int kb = kt * 64;

        // K fragments direct from global (natural layout, dk-contiguous)
        v8bf kf0[4], kf1[4];
#pragma unroll
        for (int nk = 0; nk < 4; ++nk) {
            const unsigned short* kp = &Kg[((size_t)(b * SS + kb + nk * 16 + l16)) * DD + h * 64];
            kf0[nk] = *(const v8bf*)(kp + quad * 8);
            kf1[nk] = *(const v8bf*)(kp + 32 + quad * 8);
        }
        // V^T fragments direct from global (key-contiguous)
        v8bf vf[2][4];
#pragma unroll
        for (int kc = 0; kc < 2; ++kc)
#pragma unroll
            for (int dt = 0; dt < 4; ++dt)
                vf[kc][dt] = *(const v8bf*)(&vrow[(size_t)(dt * 16 + l16) * SS + kb + kc * 32 + quad * 8]);

        // S = Q K^T (16 q-rows x 64 keys), f32 accumulate
        v4f sacc[4] = {};
#pragma unroll
        for (int nk = 0; nk < 4; ++nk) {
            sacc[nk] = mfma16(qf0, kf0[nk], sacc[nk]);
            sacc[nk] = mfma16(qf1, kf1[nk], sacc[nk]);
        }

        // scale + causal mask + online softmax (row = quad*4+r; reduce across l16)
        float pv[4][4], tmax[4], tsum[4];
#pragma unroll
        for (int r = 0; r < 4; ++r) {
            int qrow = qs + quad * 4 + r;
            float mx = -1e30f;
#pragma unroll
            for (int nk = 0; nk < 4; ++nk) {
                float s = sacc[nk][r] * scale;
                int key = kb + nk * 16 + l16;
                if (key > qrow) s = -1e30f;
                pv[nk][r] = s;
                mx = fmaxf(mx, s);
            }
            tmax[r] = mx;
        }
        for (int off = 1; off < 16; off <<= 1)
#pragma unroll
            for (int r = 0; r < 4; ++r)
                tmax[r] = fmaxf(tmax[r], __shfl_xor(tmax[r], off, 64));
#pragma unroll
        for (int r = 0; r < 4; ++r) {
            float mnew  = fmaxf(m_run[r], tmax[r]);
            float alpha = __expf(m_run[r] - mnew);
            m_run[r] = mnew;
            float s = 0.0f;
#pragma unroll
            for (int nk = 0; nk < 4; ++nk) {
                float p = __expf(pv[nk][r] - mnew);
                pv[nk][r] = p;
                s += p;
            }
            tsum[r] = s;
#pragma unroll
            for (int dt = 0; dt < 4; ++dt) oacc[dt][r] *= alpha;
            l_run[r] *= alpha;
        }
        for (int off = 1; off < 16; off <<= 1)
#pragma unroll
            for (int r = 0; r < 4; ++r)
                tsum[r] += __shfl_xor(tsum[r], off, 64);
#pragma unroll
        for (int r = 0; r < 4; ++r) l_run[r] += tsum[r];

        // P: C-layout -> per-wave LDS (stride 72) -> A-layout frags.
        // Wave-internal only; fence stops compiler reordering (R2==R4 verified).
#pragma unroll
        for (int nk = 0; nk < 4; ++nk)
#pragma unroll
            for (int r = 0; r < 4; ++r)
                pw[(quad * 4 + r) * 72 + nk * 16 + l16] = f2bf(pv[nk][r]);
        __asm__ volatile("" ::: "memory");

        v8bf pa0 = *(const v8bf*)(&pw[l16 * 72 + quad * 8]);
        v8bf pa1 = *(const v8bf*)(&pw[l16 * 72 + 32 + quad * 8]);
#pragma unroll
        for (int dt = 0; dt < 4; ++dt) oacc[dt] = mfma16(pa0, vf[0][dt], oacc[dt]);
#pragma unroll
        for (int dt = 0; dt < 4; ++dt) oacc[dt] = mfma16(pa1, vf[1][dt], oacc[dt]);
    }

    // Publish per-wave partials (idle waves publish m=-1e30, l=0, O=0 -> weight 0)
    if (l16 == 0)
#pragma unroll
        for (int r = 0; r < 4; ++r) {
            Mw[wave][quad * 4 + r] = m_run[r];
            Lw[wave][quad * 4 + r] = l_run[r];
        }
#pragma unroll
    for (int dt = 0; dt < 4; ++dt)
#pragma unroll
        for (int r = 0; r < 4; ++r)
            Ow[wave][(quad * 4 + r) * 65 + dt * 16 + l16] = oacc[dt][r];

    __syncthreads();

    // Merge 4 partials: thread handles 4 (row,dk) pairs
#pragma unroll
    for (int i = 0; i < 4; ++i) {
        int p = tid + i * 256;           // 0..1023
        int row = p >> 6, dk = p & 63;
        float M = fmaxf(fmaxf(Mw[0][row], Mw[1][row]), fmaxf(Mw[2][row], Mw[3][row]));
        float acc = 0.0f, l = 0.0f;
#pragma unroll
        for (int w = 0; w < 4; ++w) {
            float al = __expf(Mw[w][row] - M);
            acc += al * Ow[w][row * 65 + dk];
            l   += al * Lw[w][row];
        }
        O[((size_t)(b * SS + qs + row)) * DD + h * 64 + dk] = f2bf(acc / l);
    }
}

// ---------------------------------------------------------------------------
extern "C" void kernel_launch(void* const* d_in, const int* in_sizes, int n_in,
                              void* d_out, int out_size, void* d_ws, size_t ws_size,
                              hipStream_t stream)
{
    const float* X  = (const float*)d_in[0];
    const float* Wq = (const float*)d_in[1];
    const float* Wk = (const float*)d_in[2];
    const float* Wv = (const float*)d_in[3];
    const float* Wo = (const float*)d_in[4];
    float* Out = (float*)d_out;

    // ws layout (elements of u16): Qb[XSZ] Kb[XSZ] | Xb[XSZ] Wqb Wkb Wvb Wob[WSZ each]
    unsigned short* Qb  = (unsigned short*)d_ws;
    unsigned short* Kb  = Qb + XSZ;
    unsigned short* Vtb = (unsigned short*)d_out;   // V^T (6.29 MB), dead before out-proj
    const size_t need_pre = (3 * (size_t)XSZ + 4 * (size_t)WSZ) * sizeof(unsigned short);
    const bool pre = (ws_size >= need_pre);         // deterministic per session

    dim3 blk(256);
    dim3 g1(DD / 128, MM / 128, 3);
    dim3 g2(SS / 16, HH, BB);
    dim3 g3(DD / 128, MM / 128, 1);

    if (pre) {
        unsigned short* Xb  = Kb + XSZ;
        unsigned short* Wqb = Xb + XSZ;
        unsigned short* Wkb = Wqb + WSZ;
        unsigned short* Wvb = Wkb + WSZ;
        unsigned short* Wob = Wvb + WSZ;
        cvt_all<<<5376, blk, 0, stream>>>(X, Wq, Wk, Wv, Wo, Xb, Wqb, Wkb, Wvb, Wob);
        gemm_u<1, 1, 0, 1><<<g1, blk, 0, stream>>>(Xb, Wqb, Wkb, Wvb, Qb, Kb, Vtb);
        attn_wf<<<g2, blk, 0, stream>>>(Qb, Kb, Vtb, Qb);
        gemm_u<1, 1, 1, 0><<<g3, blk, 0, stream>>>(Qb, Wob, Wob, Wob, Out, Out, Out);
    } else {
        gemm_u<0, 0, 0, 1><<<g1, blk, 0, stream>>>(X, Wq, Wk, Wv, Qb, Kb, Vtb);
        attn_wf<<<g2, blk, 0, stream>>>(Qb, Kb, Vtb, Qb);
        gemm_u<1, 0, 1, 0><<<g3, blk, 0, stream>>>(Qb, Wo, Wo, Wo, Out, Out, Out);
    }
}